// Round 16
// baseline (18.151 us; speedup 1.0000x reference)
//
#include <hip/hip_runtime.h>
#include <math.h>

// Problem constants: Q=4, N=64, H=256, C=1, L=1024
#define QQ 4
#define NN 64
#define HH 256

// SINGLE kernel, 1024 blocks x 256 threads (R15 structure).
// Block b -> qh via XCD-aware swizzle (qh = (b%8)*128 + b/8).
// Phase A: LDS pole table (2 poles / 3 x float4), two bins per thread in
//   packed 2xf32 (v_pk_fma_f32); tan via HW v_sin/v_cos.
// Phase B: 512-pt complex inverse FFT, RADIX-4 Stockham: reg radix-2
//   (Ns=1) + 3 LDS radix-4 stages (Ns=2,8,32) + final radix-4 (Ns=128)
//   straight to global scatter store. 5 barriers vs 9, ~half FFT LDS ops.
//   Radix-4 verified against the radix-2 ladder (N=8 hand-check): one
//   stage at Ns == radix-2 stages (Ns, 2Ns) incl. output placement.

typedef float f2 __attribute__((ext_vector_type(2)));

__device__ __forceinline__ float vcos(float rev) { return __builtin_amdgcn_cosf(rev); }
__device__ __forceinline__ float vsin(float rev) { return __builtin_amdgcn_sinf(rev); }

__global__ __launch_bounds__(256)
void tssm_kernel(const float* __restrict__ diagonal,      // [Q][N]
                 const float* __restrict__ lowrank,       // [Q][N]
                 const float* __restrict__ timestep,      // [Q][H]
                 const float* __restrict__ input_matrix,  // [Q][N]
                 const float* __restrict__ output_matrix, // [Q][1][H][N]
                 float* __restrict__ out)                 // [L][Q][1][H]
{
    __shared__ __align__(16) float2 bufA[512];
    __shared__ __align__(16) float2 bufB[513];
    __shared__ __align__(16) float  sPf[NN * 6];   // 2 poles per 12 floats

    const int b  = blockIdx.x;                  // 0..1023
    const int qh = ((b & 7) << 7) + (b >> 3);   // XCD-aware swizzle
    const int q  = qh >> 8;
    const int t  = threadIdx.x;

    const float tv   = __expf(timestep[qh]);
    const float invt = __builtin_amdgcn_rcpf(tv);

    // ---- pole table setup (wave 0) + X[512] ----
    if (t < NN) {
        float a  = __expf(diagonal[q * NN + t]);
        float B  = input_matrix[q * NN + t];
        float P  = lowrank[q * NN + t];
        float Cm = output_matrix[qh * NN + t];
        float w0 = B * Cm;
        const int base = (t >> 1) * 12 + (t & 1) * 6;
        sPf[base + 0] = a;
        sPf[base + 1] = a * a;
        sPf[base + 2] = w0;
        sPf[base + 3] = B * P;
        sPf[base + 4] = P * Cm;
        sPf[base + 5] = P * P;
        float acc = w0;
        #pragma unroll
        for (int off = 32; off >= 1; off >>= 1) acc += __shfl_xor(acc, off, 64);
        if (t == 0) bufB[512] = make_float2(0.5f * tv * acc, 0.0f);
    }
    __syncthreads();

    // ---------------- Phase A: bins l = t and l = t+256 (packed 2xf32) ----
    const float rv0 = (float)t         * (1.0f / 2048.0f);
    const float rv1 = (float)(t + 256) * (1.0f / 2048.0f);
    const float tn0 = vsin(rv0) * __builtin_amdgcn_rcpf(vcos(rv0));
    const float tn1 = vsin(rv1) * __builtin_amdgcn_rcpf(vcos(rv1));
    const float ze0 = 2.0f * tn0 * invt, ze1 = 2.0f * tn1 * invt;

    const f2 z2v = { ze0 * ze0, ze1 * ze1 };

    f2 r_0 = 0.0f, r_1 = 0.0f, r_2 = 0.0f, r_3 = 0.0f;
    f2 s_0 = 0.0f, s_1 = 0.0f, s_2 = 0.0f, s_3 = 0.0f;

    #define POLE(PA, PA2, PW0, PW1, PW2, PW3)                                \
    {                                                                        \
        f2 d = (PA2) + z2v;                                                  \
        f2 g;                                                                \
        g.x = __builtin_amdgcn_rcpf(d.x);                                    \
        g.y = __builtin_amdgcn_rcpf(d.y);                                    \
        f2 ag = (PA) * g;                                                    \
        r_0 = __builtin_elementwise_fma((f2)(PW0), ag, r_0);                 \
        s_0 = __builtin_elementwise_fma((f2)(PW0), g,  s_0);                 \
        r_1 = __builtin_elementwise_fma((f2)(PW1), ag, r_1);                 \
        s_1 = __builtin_elementwise_fma((f2)(PW1), g,  s_1);                 \
        r_2 = __builtin_elementwise_fma((f2)(PW2), ag, r_2);                 \
        s_2 = __builtin_elementwise_fma((f2)(PW2), g,  s_2);                 \
        r_3 = __builtin_elementwise_fma((f2)(PW3), ag, r_3);                 \
        s_3 = __builtin_elementwise_fma((f2)(PW3), g,  s_3);                 \
    }

    {
        const float4* __restrict__ T4 = (const float4*)sPf;
        #pragma unroll 4
        for (int p = 0; p < 32; ++p) {
            float4 Av = T4[3 * p];
            float4 Bv = T4[3 * p + 1];
            float4 Cv = T4[3 * p + 2];
            POLE(Av.x, Av.y, Av.z, Av.w, Bv.x, Bv.y)
            POLE(Bv.z, Bv.w, Cv.x, Cv.y, Cv.z, Cv.w)
        }
    }
    #undef POLE

    {   // bin l = t
        float i0 = -ze0 * s_0.x, i1 = -ze0 * s_1.x, i2 = -ze0 * s_2.x, i3 = -ze0 * s_3.x;
        float dr = 1.0f + r_3.x, di = i3;
        float nr = r_2.x * r_1.x - i2 * i1;
        float ni = r_2.x * i1 + i2 * r_1.x;
        float invm = __builtin_amdgcn_rcpf(fmaf(dr, dr, di * di));
        float qr = (nr * dr + ni * di) * invm;
        float qi = (ni * dr - nr * di) * invm;
        float Kr = r_0.x - qr, Ki = i0 - qi;
        bufB[t] = make_float2(fmaf(-tn0, Ki, Kr), fmaf(tn0, Kr, Ki));
    }
    {   // bin l = t + 256
        float i0 = -ze1 * s_0.y, i1 = -ze1 * s_1.y, i2 = -ze1 * s_2.y, i3 = -ze1 * s_3.y;
        float dr = 1.0f + r_3.y, di = i3;
        float nr = r_2.y * r_1.y - i2 * i1;
        float ni = r_2.y * i1 + i2 * r_1.y;
        float invm = __builtin_amdgcn_rcpf(fmaf(dr, dr, di * di));
        float qr = (nr * dr + ni * di) * invm;
        float qi = (ni * dr - nr * di) * invm;
        float Kr = r_0.y - qr, Ki = i0 - qi;
        bufB[t + 256] = make_float2(fmaf(-tn1, Ki, Kr), fmaf(tn1, Kr, Ki));
    }
    __syncthreads();

    // ---------------- Y build ----------------
    const float c1 = vcos((float)t * 0.0009765625f);   // cos(2*pi*t/1024)
    const float s1 = vsin((float)t * 0.0009765625f);

    float Y0r, Y0i, Y1r, Y1i;
    {   // k = t
        float2 A = bufB[t], Bv = bufB[512 - t];
        float Dr = A.x - Bv.x, Di = A.y + Bv.y;
        float twDr = fmaf(c1, Dr, -s1 * Di);
        float twDi = fmaf(c1, Di,  s1 * Dr);
        Y0r = 0.5f * (A.x + Bv.x) - 0.5f * twDi;
        Y0i = 0.5f * (A.y - Bv.y) + 0.5f * twDr;
    }
    {   // k = t+256
        float2 A = bufB[t + 256], Bv = bufB[256 - t];
        float Dr = A.x - Bv.x, Di = A.y + Bv.y;
        float twDr = fmaf(-s1, Dr, -c1 * Di);
        float twDi = fmaf(-s1, Di,  c1 * Dr);
        Y1r = 0.5f * (A.x + Bv.x) - 0.5f * twDi;
        Y1i = 0.5f * (A.y - Bv.y) + 0.5f * twDr;
    }

    // ---------------- Stage Ns=1 radix-2 (registers) -> bufA ----------------
    ((float4*)bufA)[t] = make_float4(Y0r + Y1r, Y0i + Y1i, Y0r - Y1r, Y0i - Y1i);
    __syncthreads();

    // ---------------- Radix-4 Stockham stages (threads 0..127) ----------------
    // One stage at Ns == radix-2 stages (Ns, 2Ns). Inputs stride 128; twiddle
    // tw_q = e^{+2pi i q base/(4Ns)}; y_r = sum_q tw_q u_q i^{qr};
    // outputs dst[blk*4Ns + base + r*Ns].
    #define FFT_STAGE4(NS, REVNS, SRC, DST)                                   \
    if (t < 128) {                                                            \
        int base = t & ((NS) - 1);                                            \
        int blk  = t / (NS);                                                  \
        float2 u0 = (SRC)[t],       u1 = (SRC)[t + 128];                      \
        float2 u2 = (SRC)[t + 256], u3 = (SRC)[t + 384];                      \
        float rev = (float)base * (REVNS);                                    \
        float c1v = vcos(rev),          s1w = vsin(rev);                      \
        float c2v = vcos(2.0f * rev),   s2w = vsin(2.0f * rev);               \
        float c3v = vcos(3.0f * rev),   s3w = vsin(3.0f * rev);               \
        float v1r = fmaf(c1v, u1.x, -s1w * u1.y);                             \
        float v1i = fmaf(c1v, u1.y,  s1w * u1.x);                             \
        float v2r = fmaf(c2v, u2.x, -s2w * u2.y);                             \
        float v2i = fmaf(c2v, u2.y,  s2w * u2.x);                             \
        float v3r = fmaf(c3v, u3.x, -s3w * u3.y);                             \
        float v3i = fmaf(c3v, u3.y,  s3w * u3.x);                             \
        float ar = u0.x + v2r, ai = u0.y + v2i;                               \
        float br = u0.x - v2r, bi = u0.y - v2i;                               \
        float cr = v1r + v3r,  ci = v1i + v3i;                                \
        float dr2 = v1r - v3r, di2 = v1i - v3i;                               \
        int dj = blk * (4 * (NS)) + base;                                     \
        (DST)[dj]            = make_float2(ar + cr,  ai + ci);                \
        (DST)[dj + (NS)]     = make_float2(br - di2, bi + dr2);               \
        (DST)[dj + 2*(NS)]   = make_float2(ar - cr,  ai - ci);                \
        (DST)[dj + 3*(NS)]   = make_float2(br + di2, bi - dr2);               \
    }                                                                         \
    __syncthreads();

    FFT_STAGE4(2,  0.125f,      bufA, bufB)
    FFT_STAGE4(8,  0.03125f,    bufB, bufA)
    FFT_STAGE4(32, 0.0078125f,  bufA, bufB)
    #undef FFT_STAGE4

    // -------- Final radix-4 stage (Ns=128) -> direct scatter to out --------
    if (t < 128) {
        float2 u0 = bufB[t],       u1 = bufB[t + 128];
        float2 u2 = bufB[t + 256], u3 = bufB[t + 384];
        float rev = (float)t * 0.001953125f;         // t/512
        float c1v = vcos(rev),          s1w = vsin(rev);
        float c2v = vcos(2.0f * rev),   s2w = vsin(2.0f * rev);
        float c3v = vcos(3.0f * rev),   s3w = vsin(3.0f * rev);
        float v1r = fmaf(c1v, u1.x, -s1w * u1.y);
        float v1i = fmaf(c1v, u1.y,  s1w * u1.x);
        float v2r = fmaf(c2v, u2.x, -s2w * u2.y);
        float v2i = fmaf(c2v, u2.y,  s2w * u2.x);
        float v3r = fmaf(c3v, u3.x, -s3w * u3.y);
        float v3i = fmaf(c3v, u3.y,  s3w * u3.x);
        float ar = u0.x + v2r, ai = u0.y + v2i;
        float br = u0.x - v2r, bi = u0.y - v2i;
        float cr = v1r + v3r,  ci = v1i + v3i;
        float dr2 = v1r - v3r, di2 = v1i - v3i;
        const float sc = 1.0f / 512.0f;
        // y_r at m = t + r*128 ; x[2m] = Re, x[2m+1] = Im (scaled)
        const int s0 = 2 * t;
        out[( s0          << 10) + qh] = (ar + cr)  * sc;
        out[((s0 + 1)     << 10) + qh] = (ai + ci)  * sc;
        out[((s0 + 256)   << 10) + qh] = (br - di2) * sc;
        out[((s0 + 257)   << 10) + qh] = (bi + dr2) * sc;
        out[((s0 + 512)   << 10) + qh] = (ar - cr)  * sc;
        out[((s0 + 513)   << 10) + qh] = (ai - ci)  * sc;
        out[((s0 + 768)   << 10) + qh] = (br + di2) * sc;
        out[((s0 + 769)   << 10) + qh] = (bi - dr2) * sc;
    }
}

extern "C" void kernel_launch(void* const* d_in, const int* in_sizes, int n_in,
                              void* d_out, int out_size, void* d_ws, size_t ws_size,
                              hipStream_t stream) {
    (void)in_sizes; (void)n_in; (void)out_size; (void)d_ws; (void)ws_size;
    const float* diagonal      = (const float*)d_in[0];
    const float* lowrank       = (const float*)d_in[1];
    const float* timestep      = (const float*)d_in[2];
    const float* input_matrix  = (const float*)d_in[3];
    const float* output_matrix = (const float*)d_in[4];
    float* out = (float*)d_out;

    hipLaunchKernelGGL(tssm_kernel, dim3(QQ * HH), dim3(256), 0, stream,
                       diagonal, lowrank, timestep, input_matrix, output_matrix, out);
}